// Round 2
// baseline (435.403 us; speedup 1.0000x reference)
//
#include <hip/hip_runtime.h>
#include <hip/hip_bf16.h>

typedef __attribute__((ext_vector_type(8))) short bf16x8;
typedef __attribute__((ext_vector_type(4))) float f32x4;
typedef unsigned short u16;
typedef unsigned int u32;

__device__ __forceinline__ u32 bf16_rne(float f) {
  u32 u = __float_as_uint(f);
  return (u + 0x7FFFu + ((u >> 16) & 1u)) >> 16;
}
__device__ __forceinline__ float bf16_val(u32 b) { return __uint_as_float(b << 16); }

// ---- transpose each 256x256 fp32 slice and split into bf16 hi/lo arrays ----
__global__ void split_transpose256(const float* __restrict__ in,
                                   u16* __restrict__ hi, u16* __restrict__ lo) {
  __shared__ float tile[32][33];
  const size_t off = (size_t)blockIdx.z * 65536;
  const int tx = threadIdx.x, ty = threadIdx.y;
#pragma unroll
  for (int i = 0; i < 4; ++i) {
    int y = blockIdx.y * 32 + ty + i * 8;
    int x = blockIdx.x * 32 + tx;
    tile[ty + i * 8][tx] = in[off + (size_t)y * 256 + x];
  }
  __syncthreads();
#pragma unroll
  for (int i = 0; i < 4; ++i) {
    float v = tile[tx][ty + i * 8];
    u32 hb = bf16_rne(v);
    u32 lb = bf16_rne(v - bf16_val(hb));
    size_t idx = off + (size_t)(blockIdx.x * 32 + ty + i * 8) * 256 + blockIdx.y * 32 + tx;
    hi[idx] = (u16)hb;
    lo[idx] = (u16)lb;
  }
}

// ---------------- fused priors-GEMM (split-bf16) + dynamic routing ----------------
// One block per (kk, a). P[b,e] (R x 256) resident in MFMA accumulators:
// row b = mt*16 + q*4 + r, col e = w*64 + ct*16 + li.
template <int R>
__global__ __launch_bounds__(256, 2) void caps_route(
    const float* __restrict__ Amat,   // [64][R][256] fp32
    const u16* __restrict__ Whi,      // [KN][256][256] bf16 (transposed: [e][d])
    const u16* __restrict__ Wlo,
    float* __restrict__ outp,
    int KN, int stage) {
  constexpr int MT = R / 16;
  __shared__ u16 Ahi[R * 40];         // padded stride 40 elems (80 B)
  __shared__ u16 Alo[R * 40];
  __shared__ u16 Bhi[256 * 40];
  __shared__ u16 Blo[256 * 40];
  __shared__ __align__(16) float wlog[4][R];
  __shared__ float logits[R];
  __shared__ __align__(16) float probs[R];
  __shared__ float sqpart[4];

  const int tid = threadIdx.x;
  const int w = tid >> 6, lane = tid & 63, q = lane >> 4, li = lane & 15;
  const int kk = blockIdx.x >> 6;   // weight slice (h or c)
  const int a  = blockIdx.x & 63;

  const float* Arow = Amat + (size_t)a * R * 256;
  const u16* Whrow = Whi + (size_t)kk * 65536;
  const u16* Wlrow = Wlo + (size_t)kk * 65536;

  f32x4 acc[MT][4] = {};

  // ---- GEMM: P = A (R x 256, fp32 -> hi/lo bf16) @ W[kk] (256 x 256) ----
  for (int ks = 0; ks < 8; ++ks) {
    const int k0 = ks * 32;
    // A staging: fp32 -> split bf16
#pragma unroll
    for (int c = tid; c < R * 8; c += 256) {
      int row = c >> 3, p = c & 7;
      float4 vv = *(const float4*)(Arow + row * 256 + k0 + p * 4);
      u32 h0 = bf16_rne(vv.x), h1 = bf16_rne(vv.y), h2 = bf16_rne(vv.z), h3 = bf16_rne(vv.w);
      u32 l0 = bf16_rne(vv.x - bf16_val(h0));
      u32 l1 = bf16_rne(vv.y - bf16_val(h1));
      u32 l2 = bf16_rne(vv.z - bf16_val(h2));
      u32 l3 = bf16_rne(vv.w - bf16_val(h3));
      uint2 hv; hv.x = h0 | (h1 << 16); hv.y = h2 | (h3 << 16);
      uint2 lv; lv.x = l0 | (l1 << 16); lv.y = l2 | (l3 << 16);
      *(uint2*)((char*)Ahi + row * 80 + p * 8) = hv;
      *(uint2*)((char*)Alo + row * 80 + p * 8) = lv;
    }
    // B staging: already bf16 hi/lo, rows are e
#pragma unroll
    for (int c = tid; c < 1024; c += 256) {
      int row = c >> 2, p = c & 3;
      int4 vh = *(const int4*)(Whrow + row * 256 + k0 + p * 8);
      int4 vl = *(const int4*)(Wlrow + row * 256 + k0 + p * 8);
      *(int4*)((char*)Bhi + row * 80 + p * 16) = vh;
      *(int4*)((char*)Blo + row * 80 + p * 16) = vl;
    }
    __syncthreads();
    bf16x8 bh[4], bl[4];
#pragma unroll
    for (int ct = 0; ct < 4; ++ct) {
      int e = w * 64 + ct * 16 + li;
      bh[ct] = *(const bf16x8*)((const char*)Bhi + e * 80 + q * 16);
      bl[ct] = *(const bf16x8*)((const char*)Blo + e * 80 + q * 16);
    }
#pragma unroll
    for (int mt = 0; mt < MT; ++mt) {
      bf16x8 ah = *(const bf16x8*)((const char*)Ahi + (mt * 16 + li) * 80 + q * 16);
      bf16x8 al = *(const bf16x8*)((const char*)Alo + (mt * 16 + li) * 80 + q * 16);
#pragma unroll
      for (int ct = 0; ct < 4; ++ct) {
        acc[mt][ct] = __builtin_amdgcn_mfma_f32_16x16x32_bf16(al, bh[ct], acc[mt][ct], 0, 0, 0);
        acc[mt][ct] = __builtin_amdgcn_mfma_f32_16x16x32_bf16(ah, bl[ct], acc[mt][ct], 0, 0, 0);
        acc[mt][ct] = __builtin_amdgcn_mfma_f32_16x16x32_bf16(ah, bh[ct], acc[mt][ct], 0, 0, 0);
      }
    }
    __syncthreads();
  }

  // ---- dynamic routing (3 iterations) on register-resident P ----
  float pr[MT][4];
  float v[4];
  const float invR = 1.0f / R;
#pragma unroll
  for (int mt = 0; mt < MT; ++mt)
#pragma unroll
    for (int r = 0; r < 4; ++r) pr[mt][r] = invR;

  for (int iter = 0; iter < 3; ++iter) {
    if (iter > 0) {
#pragma unroll
      for (int mt = 0; mt < MT; ++mt) {
        float4 p4 = *(const float4*)&probs[mt * 16 + q * 4];
        pr[mt][0] = p4.x; pr[mt][1] = p4.y; pr[mt][2] = p4.z; pr[mt][3] = p4.w;
      }
    }
    // s[e] = sum_b probs[b] * P[b,e]
    float s[4];
#pragma unroll
    for (int ct = 0; ct < 4; ++ct) {
      float t = 0.f;
#pragma unroll
      for (int mt = 0; mt < MT; ++mt)
#pragma unroll
        for (int r = 0; r < 4; ++r) t += pr[mt][r] * acc[mt][ct][r];
      t += __shfl_xor(t, 16);
      t += __shfl_xor(t, 32);
      s[ct] = t;
    }
    // squash
    float ss = s[0] * s[0] + s[1] * s[1] + s[2] * s[2] + s[3] * s[3];
    ss += __shfl_xor(ss, 1);
    ss += __shfl_xor(ss, 2);
    ss += __shfl_xor(ss, 4);
    ss += __shfl_xor(ss, 8);
    if (lane == 0) sqpart[w] = ss;
    __syncthreads();
    float sq = sqpart[0] + sqpart[1] + sqpart[2] + sqpart[3];
    float scale = (sq > 0.f) ? sq / ((1.0f + sq) * sqrtf(sq)) : 0.f;
#pragma unroll
    for (int ct = 0; ct < 4; ++ct) v[ct] = s[ct] * scale;

    if (iter < 2) {
      // logits[b] += sum_e P[b,e] * v[e]
      float part[MT][4];
#pragma unroll
      for (int mt = 0; mt < MT; ++mt) {
#pragma unroll
        for (int r = 0; r < 4; ++r) {
          float t = acc[mt][0][r] * v[0] + acc[mt][1][r] * v[1] +
                    acc[mt][2][r] * v[2] + acc[mt][3][r] * v[3];
          t += __shfl_xor(t, 1);
          t += __shfl_xor(t, 2);
          t += __shfl_xor(t, 4);
          t += __shfl_xor(t, 8);
          part[mt][r] = t;
        }
      }
      __syncthreads();
      if (li == 0) {
#pragma unroll
        for (int mt = 0; mt < MT; ++mt) {
          *(float4*)&wlog[w][mt * 16 + q * 4] =
              make_float4(part[mt][0], part[mt][1], part[mt][2], part[mt][3]);
        }
      }
      __syncthreads();
      if (tid < R) {
        float l = (iter == 0 ? 0.f : logits[tid]) +
                  wlog[0][tid] + wlog[1][tid] + wlog[2][tid] + wlog[3][tid];
        logits[tid] = l;
      }
      __syncthreads();
      if (w == 0) {  // softmax over R logits, wave 0
        float l0 = logits[lane];
        float l1 = (R == 128) ? logits[lane + 64] : -3.0e38f;
        float m = fmaxf(l0, l1);
#pragma unroll
        for (int d2 = 1; d2 < 64; d2 <<= 1) m = fmaxf(m, __shfl_xor(m, d2));
        float e0 = expf(l0 - m);
        float e1 = (R == 128) ? expf(l1 - m) : 0.f;
        float zz = e0 + e1;
#pragma unroll
        for (int d2 = 1; d2 < 64; d2 <<= 1) zz += __shfl_xor(zz, d2);
        float inv = 1.0f / zz;
        probs[lane] = e0 * inv;
        if (R == 128) probs[lane + 64] = e1 * inv;
      }
      __syncthreads();
    }
  }

  // ---- write v (fp32). stage1 -> out1[a][kk][e]; stage2 -> out[kk][a][e] ----
  size_t obase = (stage == 1) ? ((size_t)a * KN + kk) * 256
                              : ((size_t)kk * 64 + a) * 256;
  if (q == 0) {
#pragma unroll
    for (int ct = 0; ct < 4; ++ct) {
      int e = w * 64 + ct * 16 + li;
      outp[obase + e] = v[ct];
    }
  }
}

extern "C" void kernel_launch(void* const* d_in, const int* in_sizes, int n_in,
                              void* d_out, int out_size, void* d_ws, size_t ws_size,
                              hipStream_t stream) {
  const float* x  = (const float*)d_in[0];   // [64][128][256]
  const float* w1 = (const float*)d_in[1];   // [64][256][256]
  const float* wc = (const float*)d_in[2];   // [32][256][256]
  float* out = (float*)d_out;                // [32][64][256]

  char* ws = (char*)d_ws;
  u16*   w1hi = (u16*)ws;                       // 8,388,608 B
  u16*   w1lo = (u16*)(ws + 8388608);           // 8,388,608 B
  u16*   wchi = (u16*)(ws + 16777216);          // 4,194,304 B
  u16*   wclo = (u16*)(ws + 20971520);          // 4,194,304 B
  float* out1 = (float*)(ws + 25165824);        // 4,194,304 B  [64][64][256] fp32

  split_transpose256<<<dim3(8, 8, 64), dim3(32, 8), 0, stream>>>(w1, w1hi, w1lo);
  split_transpose256<<<dim3(8, 8, 32), dim3(32, 8), 0, stream>>>(wc, wchi, wclo);
  caps_route<128><<<64 * 64, 256, 0, stream>>>(x, w1hi, w1lo, out1, 64, 1);
  caps_route<64><<<32 * 64, 256, 0, stream>>>(out1, wchi, wclo, out, 32, 2);
}